// Round 1
// baseline (211.762 us; speedup 1.0000x reference)
//
#include <hip/hip_runtime.h>
#include <math.h>

#define NROWS 8192
#define DIMX  1024
#define DKV   128
#define KSPLIT 4
#define KEYS_PER_SPLIT (NROWS / KSPLIT)  // 2048
#define BN 64

typedef __attribute__((ext_vector_type(8))) short bf16x8;
typedef __attribute__((ext_vector_type(4))) float f32x4;

static __device__ __forceinline__ short f2bf(float f) {
    union { float f; unsigned u; } v; v.f = f;
    unsigned r = v.u + 0x7fff + ((v.u >> 16) & 1);  // RNE
    return (short)(r >> 16);
}

// ---------------------------------------------------------------------------
// proj: qkb[N][128] = bf16(x @ Wqk^T + bqk); vtb[128][N] = bf16(x @ Wv^T + bv)^T
// grid 128 blocks (64 rows each), 256 threads (4 waves, 16 rows/wave)
// ---------------------------------------------------------------------------
__global__ __launch_bounds__(256) void proj_kernel(
    const float* __restrict__ x,
    const float* __restrict__ Wqk, const float* __restrict__ bqk,
    const float* __restrict__ Wv,  const float* __restrict__ bv,
    short* __restrict__ qkb, short* __restrict__ vtb)
{
    __shared__ __align__(16) short xs[64 * 72];    // 64 rows x 64 d (+8 pad)
    __shared__ __align__(16) short wq[128 * 72];
    __shared__ __align__(16) short wv[128 * 72];

    const int tid  = threadIdx.x;
    const int lane = tid & 63;
    const int wave = tid >> 6;
    const int l15  = lane & 15;
    const int quad = lane >> 4;
    const int rbase = blockIdx.x * 64;

    f32x4 accq[8], accv[8];
    for (int i = 0; i < 8; ++i) { accq[i] = (f32x4)0.0f; accv[i] = (f32x4)0.0f; }

    for (int dc = 0; dc < DIMX; dc += 64) {
        __syncthreads();
        // stage x tile (fp32 -> bf16)
        for (int i = 0; i < 4; ++i) {
            int idx = i * 256 + tid;          // float4 chunk index
            int row = idx >> 4, c4 = idx & 15;
            const float4 f = *(const float4*)(x + (size_t)(rbase + row) * DIMX + dc + c4 * 4);
            short* dst = &xs[row * 72 + c4 * 4];
            dst[0] = f2bf(f.x); dst[1] = f2bf(f.y); dst[2] = f2bf(f.z); dst[3] = f2bf(f.w);
        }
        // stage Wqk, Wv tiles
        for (int i = 0; i < 8; ++i) {
            int idx = i * 256 + tid;
            int row = idx >> 4, c4 = idx & 15;
            const float4 fq = *(const float4*)(Wqk + (size_t)row * DIMX + dc + c4 * 4);
            short* dq = &wq[row * 72 + c4 * 4];
            dq[0] = f2bf(fq.x); dq[1] = f2bf(fq.y); dq[2] = f2bf(fq.z); dq[3] = f2bf(fq.w);
            const float4 fv = *(const float4*)(Wv + (size_t)row * DIMX + dc + c4 * 4);
            short* dv = &wv[row * 72 + c4 * 4];
            dv[0] = f2bf(fv.x); dv[1] = f2bf(fv.y); dv[2] = f2bf(fv.z); dv[3] = f2bf(fv.w);
        }
        __syncthreads();
        for (int ds = 0; ds < 64; ds += 32) {
            const bf16x8 a = *(const bf16x8*)&xs[(wave * 16 + l15) * 72 + ds + quad * 8];
            for (int nt = 0; nt < 8; ++nt) {
                const bf16x8 bq = *(const bf16x8*)&wq[(nt * 16 + l15) * 72 + ds + quad * 8];
                accq[nt] = __builtin_amdgcn_mfma_f32_16x16x32_bf16(a, bq, accq[nt], 0, 0, 0);
                const bf16x8 bw = *(const bf16x8*)&wv[(nt * 16 + l15) * 72 + ds + quad * 8];
                accv[nt] = __builtin_amdgcn_mfma_f32_16x16x32_bf16(a, bw, accv[nt], 0, 0, 0);
            }
        }
    }
    // epilogue: C layout col=lane&15, row=quad*4+reg
    const int rw = rbase + wave * 16 + quad * 4;
    for (int nt = 0; nt < 8; ++nt) {
        const int col = nt * 16 + l15;
        const float bq = bqk[col], b2 = bv[col];
        for (int r = 0; r < 4; ++r) {
            qkb[(size_t)(rw + r) * DKV + col] = f2bf(accq[nt][r] + bq);
            vtb[(size_t)col * NROWS + (rw + r)] = f2bf(accv[nt][r] + b2);
        }
    }
}

// ---------------------------------------------------------------------------
// flash: per block = 64 Q rows x one K-split (2048 keys); 4 waves x 16 rows.
// grid (128, KSPLIT), 256 threads.
// ---------------------------------------------------------------------------
__global__ __launch_bounds__(256) void flash_kernel(
    const short* __restrict__ qkb, const short* __restrict__ vtb,
    float* __restrict__ opart, float* __restrict__ mpart, float* __restrict__ lpart)
{
    __shared__ __align__(16) short kt[64 * 136];      // 64 keys x 128 d (+8 pad)
    __shared__ __align__(16) short vt[128 * 72];      // 128 d x 64 keys (+8 pad)
    __shared__ __align__(16) short pb[4 * 16 * 72];   // per-wave P: 16 rows x 64 keys

    const int tid  = threadIdx.x;
    const int lane = tid & 63;
    const int wave = tid >> 6;
    const int l15  = lane & 15;
    const int quad = lane >> 4;
    const int rbase = blockIdx.x * 64 + wave * 16;
    const int ks = blockIdx.y;

    // Q fragments: A layout A[m=lane&15][k=quad*8+j], resident all loop
    bf16x8 qf[4];
    {
        const short* qrow = qkb + (size_t)(rbase + l15) * DKV;
        for (int k = 0; k < 4; ++k)
            qf[k] = *(const bf16x8*)(qrow + k * 32 + quad * 8);
    }

    f32x4 oacc[8];
    for (int i = 0; i < 8; ++i) oacc[i] = (f32x4)0.0f;
    float m[4] = {-INFINITY, -INFINITY, -INFINITY, -INFINITY};
    float l[4] = {0.f, 0.f, 0.f, 0.f};

    const int j_begin = ks * KEYS_PER_SPLIT;
    for (int j0 = j_begin; j0 < j_begin + KEYS_PER_SPLIT; j0 += BN) {
        __syncthreads();   // previous iteration's LDS reads done
        // stage K tile (rows of qkb are contiguous 256B)
        for (int i = 0; i < 4; ++i) {
            int idx = i * 256 + tid;
            int row = idx >> 4, ch = idx & 15;
            *(uint4*)&kt[row * 136 + ch * 8] =
                *(const uint4*)(qkb + (size_t)(j0 + row) * DKV + ch * 8);
        }
        // stage V^T tile
        for (int i = 0; i < 4; ++i) {
            int idx = i * 256 + tid;
            int row = idx >> 3, ch = idx & 7;
            *(uint4*)&vt[row * 72 + ch * 8] =
                *(const uint4*)(vtb + (size_t)row * NROWS + j0 + ch * 8);
        }
        __syncthreads();

        // S = Q K^T : 4 n-tiles of 16 keys, K=128 in 4 steps
        f32x4 s[4];
        for (int nt = 0; nt < 4; ++nt) {
            f32x4 acc = (f32x4)0.0f;
            for (int k = 0; k < 4; ++k) {
                const bf16x8 b = *(const bf16x8*)&kt[(nt * 16 + l15) * 136 + k * 32 + quad * 8];
                acc = __builtin_amdgcn_mfma_f32_16x16x32_bf16(qf[k], b, acc, 0, 0, 0);
            }
            s[nt] = acc;
        }

        // online softmax (rows = quad*4+r, wave-private)
        float mnew[4], alpha[4];
        for (int r = 0; r < 4; ++r) {
            float mx = fmaxf(fmaxf(s[0][r], s[1][r]), fmaxf(s[2][r], s[3][r]));
            for (int off = 1; off < 16; off <<= 1)
                mx = fmaxf(mx, __shfl_xor(mx, off));
            mnew[r] = fmaxf(m[r], mx);
            alpha[r] = __expf(m[r] - mnew[r]);
        }
        float rs[4];
        for (int r = 0; r < 4; ++r) {
            float sum = 0.f;
            for (int nt = 0; nt < 4; ++nt) {
                float p = __expf(s[nt][r] - mnew[r]);
                s[nt][r] = p;
                sum += p;
            }
            for (int off = 1; off < 16; off <<= 1)
                sum += __shfl_xor(sum, off);
            rs[r] = sum;
        }
        for (int r = 0; r < 4; ++r) {
            l[r] = l[r] * alpha[r] + rs[r];
            m[r] = mnew[r];
        }
        for (int nt = 0; nt < 8; ++nt)
            for (int r = 0; r < 4; ++r)
                oacc[nt][r] *= alpha[r];

        // P: C layout -> LDS -> A layout (per-wave buffer)
        short* pw = &pb[wave * 16 * 72];
        for (int nt = 0; nt < 4; ++nt)
            for (int r = 0; r < 4; ++r)
                pw[(quad * 4 + r) * 72 + nt * 16 + l15] = f2bf(s[nt][r]);
        __syncthreads();

        // O += P V : 8 d-tiles, 64 keys in 2 k-steps
        for (int k = 0; k < 2; ++k) {
            const bf16x8 a = *(const bf16x8*)&pw[l15 * 72 + k * 32 + quad * 8];
            for (int nt = 0; nt < 8; ++nt) {
                const bf16x8 b = *(const bf16x8*)&vt[(nt * 16 + l15) * 72 + k * 32 + quad * 8];
                oacc[nt] = __builtin_amdgcn_mfma_f32_16x16x32_bf16(a, b, oacc[nt], 0, 0, 0);
            }
        }
    }

    // store partials (unnormalized O + per-row m, l)
    const int rw = rbase + quad * 4;
    for (int nt = 0; nt < 8; ++nt) {
        const int col = nt * 16 + l15;
        for (int r = 0; r < 4; ++r)
            opart[((size_t)ks * NROWS + rw + r) * DKV + col] = oacc[nt][r];
    }
    if (l15 == 0)
        for (int r = 0; r < 4; ++r) {
            mpart[ks * NROWS + rw + r] = m[r];
            lpart[ks * NROWS + rw + r] = l[r];
        }
}

// ---------------------------------------------------------------------------
// combine: merge KSPLIT partials -> out (fp32)
// ---------------------------------------------------------------------------
__global__ __launch_bounds__(256) void combine_kernel(
    const float* __restrict__ opart, const float* __restrict__ mpart,
    const float* __restrict__ lpart, float* __restrict__ out)
{
    const int idx = blockIdx.x * 256 + threadIdx.x;  // 0 .. N*128-1
    const int row = idx >> 7;
    float M = -INFINITY;
    for (int s = 0; s < KSPLIT; ++s) M = fmaxf(M, mpart[s * NROWS + row]);
    float L = 0.f, acc = 0.f;
    for (int s = 0; s < KSPLIT; ++s) {
        const float w = __expf(mpart[s * NROWS + row] - M);
        L += w * lpart[s * NROWS + row];
        acc += w * opart[(size_t)s * NROWS * DKV + idx];
    }
    out[idx] = acc / L;
}

// ---------------------------------------------------------------------------
extern "C" void kernel_launch(void* const* d_in, const int* in_sizes, int n_in,
                              void* d_out, int out_size, void* d_ws, size_t ws_size,
                              hipStream_t stream) {
    const float* x   = (const float*)d_in[0];
    const float* Wqk = (const float*)d_in[1];
    const float* bqk = (const float*)d_in[2];
    const float* Wv  = (const float*)d_in[3];
    const float* bv  = (const float*)d_in[4];
    float* out = (float*)d_out;

    char* ws = (char*)d_ws;
    short* qkb  = (short*)ws;                               // 2 MB bf16 [N][128]
    short* vtb  = (short*)(ws + (2u << 20));                // 2 MB bf16 [128][N]
    float* opart = (float*)(ws + (4u << 20));               // 16 MB fp32 [KS][N][128]
    float* mpart = (float*)(ws + (20u << 20));              // 128 KB
    float* lpart = (float*)(ws + (20u << 20) + (128u << 10));

    proj_kernel<<<dim3(NROWS / 64), 256, 0, stream>>>(x, Wqk, bqk, Wv, bv, qkb, vtb);
    flash_kernel<<<dim3(NROWS / 64, KSPLIT), 256, 0, stream>>>(qkb, vtb, opart, mpart, lpart);
    combine_kernel<<<dim3(NROWS * DKV / 256), 256, 0, stream>>>(opart, mpart, lpart, out);
}